// Round 19
// baseline (7858.685 us; speedup 1.0000x reference)
//
#include <hip/hip_runtime.h>
#include <math.h>

#define NSAMP  2048
#define LSTEPS 100
#define DDIM   512
#define TDIM   1024
#define SB     8      // samples per block
#define NTHR   1024   // threads per block (16 waves), 1 output column/thread

// Semantics locked by R15/R17 pass (absmax==0.0). HARD RULE from R16/R18:
// every float op must be a SCALAR explicit __fmul_rn/__fadd_rn — any f32x2 /
// v_pk_*_f32 path (compiler- or asm-generated) produces non-identical
// rounding on gfx950 (both failed at absmax 0.030029...).
//  - h_t[j]: flat ascending-d fp32 chain, separate mul/add roundings (no FMA).
//  - out@U : K-panels [0,512),[512,1024); per panel ascending-k fp32 add
//            chain over spiking k; merge = one rounding fl(p0+p1).
//  - state : separately-rounded fp32 ops.
// This round vs R17 (scheduling only): 1024-thread blocks -> 16 waves/CU for
// latency hiding; 8-deep pipelined scalar gather; same arithmetic spelling.
__global__ __launch_bounds__(NTHR)
void snn_fused(const float* __restrict__ X, const float* __restrict__ W,
               const float* __restrict__ U, float* __restrict__ out)
{
#pragma clang fp contract(off)
    __shared__ float xs[SB][DDIM];                   // 16 KB
    __shared__ unsigned int msk[2][SB][TDIM / 32];   // 2 KB
    __shared__ unsigned short klist[2][SB][TDIM];    // 32 KB sorted spike indices
    __shared__ int kcnt[2][SB][2];                   // [0]=count k<512, [1]=total

    const int tid  = threadIdx.x;
    const int lane = tid & 63;
    const int wv   = tid >> 6;
    const int n0   = blockIdx.x * SB;

    float syn[SB], mem[SB];
    int   cnt[SB];
#pragma unroll
    for (int s = 0; s < SB; ++s) { syn[s] = 0.0f; mem[s] = 0.0f; cnt[s] = 0; }

    if (tid < 512) ((unsigned int*)msk)[tid] = 0u;   // both mask buffers
    if (tid < 32)  ((int*)kcnt)[tid] = 0;

    const float* wp = W + tid;   // this thread's output column
    const float* uC = U + tid;

    // single-column ascending-k __fadd_rn chain, 8-deep load pipeline.
    // Identical add order to R17's chain; only load scheduling differs.
    auto gather1 = [&](const unsigned short* ls, int beg, int end) -> float {
        float a = 0.0f;
        int i = beg;
        const int n = end - beg;
        if (n >= 8) {
            const int nm = n & ~7;
            float c[8];
#pragma unroll
            for (int j = 0; j < 8; ++j) c[j] = uC[(int)ls[beg + j] << 10];
            for (i = beg; i + 8 < beg + nm; i += 8) {
                float d[8];
#pragma unroll
                for (int j = 0; j < 8; ++j) d[j] = uC[(int)ls[i + 8 + j] << 10];
#pragma unroll
                for (int j = 0; j < 8; ++j) a = __fadd_rn(a, c[j]);   // ascending k
#pragma unroll
                for (int j = 0; j < 8; ++j) c[j] = d[j];
            }
#pragma unroll
            for (int j = 0; j < 8; ++j) a = __fadd_rn(a, c[j]);
            i = beg + nm;
        }
        for (; i < end; ++i) a = __fadd_rn(a, uC[(int)ls[i] << 10]);
        return a;
    };

    int p = 0;
    for (int t = 0; t < LSTEPS; ++t) {
        // ---- stage x_t (fp32, coalesced float4; one float4 per thread) ----
        {
            const int s  = tid >> 7;             // 0..7
            const int k4 = (tid & 127) << 2;     // 0..508
            *(float4*)&xs[s][k4] =
                *(const float4*)(X + ((size_t)(n0 + s) * LSTEPS + t) * DDIM + k4);
        }
        __syncthreads();   // staging + prev-iter compaction visibility

        // ---- h_t[j]: flat ascending-d, single accumulator, mul-then-add ----
        float a32[SB];
#pragma unroll
        for (int s = 0; s < SB; ++s) a32[s] = 0.0f;

        for (int k4 = 0; k4 < DDIM; k4 += 4) {
            float4 xv[SB];
#pragma unroll
            for (int s = 0; s < SB; ++s) xv[s] = *(const float4*)&xs[s][k4];
            float wv0[4];
#pragma unroll
            for (int e = 0; e < 4; ++e) wv0[e] = wp[(k4 + e) * TDIM];
#pragma unroll
            for (int s = 0; s < SB; ++s) {
                a32[s] = __fadd_rn(a32[s], __fmul_rn(wv0[0], xv[s].x));
                a32[s] = __fadd_rn(a32[s], __fmul_rn(wv0[1], xv[s].y));
                a32[s] = __fadd_rn(a32[s], __fmul_rn(wv0[2], xv[s].z));
                a32[s] = __fadd_rn(a32[s], __fmul_rn(wv0[3], xv[s].w));
            }
        }

        // ---- out_{t-1} @ U: list-driven K-panels 512/512 ----
        float ua[SB];
#pragma unroll 1
        for (int s = 0; s < SB; ++s) {
            const unsigned short* ls = klist[p][s];
            const int clo = kcnt[p][s][0];
            const int ct  = kcnt[p][s][1];
            const float P0 = gather1(ls, 0, clo);     // k in [0,512)
            const float P1 = gather1(ls, clo, ct);    // k in [512,1024)
            ua[s] = __fadd_rn(P0, P1);                // one merge rounding
        }

        // ---- LIF update, fp32, each op separately rounded ----
        unsigned int ob = 0u;
#pragma unroll
        for (int s = 0; s < SB; ++s) {
            const float h1 = __fadd_rn(a32[s], ua[s]);           // h_t + out@U
            const bool  o  = (__fadd_rn(mem[s], -1.0f) > 0.0f);  // spike(mem-1)
            const float sn = __fadd_rn(__fmul_rn(0.25f, syn[s]), h1); // ALPHA*syn+h1
            const float mn = o ? 0.0f : __fadd_rn(mem[s], syn[s]);    // hard reset
            if (o) { cnt[s]++; ob |= (1u << s); }
            syn[s] = sn;
            mem[s] = mn;
        }

        // ---- rebuild spike mask for next step (double-buffered) ----
        if (tid < SB * (TDIM / 32)) ((unsigned int*)(msk[p ^ 1]))[tid] = 0u;
        __syncthreads();
#pragma unroll
        for (int s = 0; s < SB; ++s)
            if (ob & (1u << s))
                atomicOr(&msk[p ^ 1][s][tid >> 5], 1u << (tid & 31));
        __syncthreads();

        // ---- compact mask -> sorted index list (wave wv handles sample wv) ----
        if (wv < SB) {
            const int pn = p ^ 1;
            const int s  = wv;
            const unsigned wrd = msk[pn][s][lane >> 1];
            const unsigned w16 = (wrd >> ((lane & 1) * 16)) & 0xFFFFu;
            const int c = __popc(w16);
            int x = c;                      // inclusive scan over 64 lanes
#pragma unroll
            for (int d = 1; d < 64; d <<= 1) {
                int y = __shfl_up(x, d);
                if (lane >= d) x += y;
            }
            int pre = x - c;                // exclusive prefix
            unsigned bits = w16;
            const int base = lane * 16;
            while (bits) {
                const int b = __ffs(bits) - 1;
                bits &= bits - 1u;
                klist[pn][s][pre++] = (unsigned short)(base + b);
            }
            const int clo = __shfl(x, 31);  // spikes with k < 512
            const int ctt = __shfl(x, 63);  // total
            if (lane == 0) { kcnt[pn][s][0] = clo; kcnt[pn][s][1] = ctt; }
        }
        p ^= 1;
    }

    // ---- H = count / 100 ----
#pragma unroll
    for (int s = 0; s < SB; ++s)
        out[(size_t)(n0 + s) * TDIM + tid] = __fdiv_rn((float)cnt[s], 100.0f);
}

extern "C" void kernel_launch(void* const* d_in, const int* in_sizes, int n_in,
                              void* d_out, int out_size, void* d_ws, size_t ws_size,
                              hipStream_t stream) {
    (void)in_sizes; (void)n_in; (void)out_size; (void)d_ws; (void)ws_size;
    const float* X = (const float*)d_in[0];
    const float* W = (const float*)d_in[1];
    const float* U = (const float*)d_in[2];
    float* outp = (float*)d_out;

    dim3 grid(NSAMP / SB);   // 256 blocks, 1 per CU
    dim3 block(NTHR);        // 1024 threads = 16 waves
    hipLaunchKernelGGL(snn_fused, grid, block, 0, stream, X, W, U, outp);
}